// Round 12
// baseline (352.473 us; speedup 1.0000x reference)
//
#include <hip/hip_runtime.h>
#include <math.h>

#define BSZ   2048
#define INDIM 1024
#define QDIM  2048   // HEADS*K_DIM
#define NHT   8      // HEADS*2
#define NKEYS 512
#define HALFD 256
#define KNN   32
#define VDIM  1024
#define HEADS 4

typedef _Float16 v8h __attribute__((ext_vector_type(8)));
typedef _Float16 v4h __attribute__((ext_vector_type(4)));
typedef float    v4f __attribute__((ext_vector_type(4)));

// ---------- f32 -> {h, h/64, m=64*(a-h)} f16 plane split ----------
// A-side plane order: [h, h/64, m]; B-side: [h, m, h/64]
template<int KSHIFT, bool ASIDE>
__device__ __forceinline__ void split4(const float* __restrict__ in,
                                       _Float16* __restrict__ out, int i) {
  const long e0 = (long)i * 4;
  const int K = 1 << KSHIFT;
  const long r = e0 >> KSHIFT;
  const int k = (int)(e0 & (K - 1));
  const float4 a = *(const float4*)&in[e0];
  const float av[4] = {a.x, a.y, a.z, a.w};
  v4h hv, dv, mv;
  #pragma unroll
  for (int u = 0; u < 4; ++u) {
    const _Float16 hh = (_Float16)av[u];
    hv[u] = hh;
    mv[u] = (_Float16)((av[u] - (float)hh) * 64.0f);
    dv[u] = (_Float16)((float)hh * 0.015625f);
  }
  _Float16* base = out + r * (3L * K) + k;
  *(v4h*)(base)         = hv;
  *(v4h*)(base + K)     = ASIDE ? dv : mv;
  *(v4h*)(base + 2 * K) = ASIDE ? mv : dv;
}

__global__ __launch_bounds__(256) void split_all_kernel(
    const float* __restrict__ x, const float* __restrict__ wq, const float* __restrict__ ky,
    _Float16* __restrict__ xs, _Float16* __restrict__ wqs, _Float16* __restrict__ kys) {
  const int i = blockIdx.x * 256 + threadIdx.x;
  if (i < 524288)            split4<10, true >(x,  xs,  i);
  else if (i < 1048576)      split4<10, false>(wq, wqs, i - 524288);
  else                       split4<8,  false>(ky, kys, i - 1048576);
}

// ---------- async global->LDS 16B ----------
__device__ __forceinline__ void gload16(const _Float16* g, _Float16* l) {
  __builtin_amdgcn_global_load_lds(
      (const __attribute__((address_space(1))) unsigned int*)g,
      (__attribute__((address_space(3))) unsigned int*)l, 16, 0, 0);
}

#define WAITV4 asm volatile("s_waitcnt vmcnt(4)" ::: "memory")
#define WAITV3 asm volatile("s_waitcnt vmcnt(3)" ::: "memory")
#define WAITV0 asm volatile("s_waitcnt vmcnt(0)" ::: "memory")

// ========== GEMM1: Q'' = split(xs @ wqs^T + b), 64x128 tile ==========
// Grid 512 blocks = 2 blocks/CU (8 waves/CU). 3-buf 2-ahead counted-vmcnt
// pipeline, 36 KB LDS. Buf = [A 4KB][B0 4KB][B1 4KB]. Same 64-row x 64B
// swizzle geometry as before => bit-identical MFMA chains.
__global__ __launch_bounds__(256) void gemm1_kernel(
    const _Float16* __restrict__ A, const _Float16* __restrict__ B,
    const float* __restrict__ bias, _Float16* __restrict__ Cq) {
  __shared__ __align__(16) char smem[36864];   // 3 bufs x 12KB; epi reuses 33.8KB
  _Float16* sh = (_Float16*)smem;
  const int t = threadIdx.x;
  const int m0 = blockIdx.y * 64, n0 = blockIdx.x * 128;

  // staging: LDS dest linear; global source inverse-swizzled
  // swizzle: byte ^= ((byte>>7)&3)<<4   (within 4KB = 64 rows x 64B)
  const int o0 = t * 16;
  const int os = o0 ^ (((o0 >> 7) & 3) << 4);
  const int sr = os >> 6;            // source row (0..63)
  const int sk = (os & 63) >> 1;     // source k element (0..31)
  const _Float16* gA  = A + (size_t)(m0 + sr) * 3072 + sk;
  const _Float16* gB0 = B + (size_t)(n0 + sr) * 3072 + sk;
  const _Float16* gB1 = B + (size_t)(n0 + 64 + sr) * 3072 + sk;
  const int t8 = t * 8;

  const int lane = t & 63, w = t >> 6;
  const int fr = lane & 15, kg = lane >> 4;

  int aoff[4], boff[2];
  #pragma unroll
  for (int i = 0; i < 4; ++i) {
    const int ra = i * 16 + fr;
    aoff[i] = (ra * 64 + ((kg ^ ((ra >> 1) & 3)) * 16)) >> 1;
  }
  #pragma unroll
  for (int j = 0; j < 2; ++j) {
    const int rb = w * 32 + j * 16 + fr;
    boff[j] = ((rb * 64 + ((kg ^ ((rb >> 1) & 3)) * 16)) >> 1) + 2048;
  }

  v4f acc[4][2];
  #pragma unroll
  for (int i = 0; i < 4; ++i)
    #pragma unroll
    for (int j = 0; j < 2; ++j)
      acc[i][j] = (v4f){0.f, 0.f, 0.f, 0.f};

  const int nt = 96;   // 3072 / 32

  // prologue: stage tiles 0,1 into bufs 0,1 (6 loads in flight)
  #pragma unroll
  for (int p = 0; p < 2; ++p) {
    _Float16* bb = sh + p * 6144;
    const size_t ko = (size_t)p * 32;
    gload16(gA + ko, bb + t8);
    gload16(gB0 + ko, bb + 2048 + t8);
    gload16(gB1 + ko, bb + 4096 + t8);
  }
  WAITV3;                              // tile 0 landed (this wave)
  __builtin_amdgcn_s_barrier();
  __builtin_amdgcn_sched_barrier(0);

  int cur = 0;
  for (int tt = 0; tt < nt; ++tt) {
    const _Float16* bb = sh + cur * 6144;
    if (tt + 2 < nt) {                 // stage tile tt+2 into buf of tile tt-1
      int sb = cur + 2; if (sb >= 3) sb -= 3;
      _Float16* nb = sh + sb * 6144;
      const size_t ko = (size_t)(tt + 2) * 32;
      gload16(gA + ko, nb + t8);
      gload16(gB0 + ko, nb + 2048 + t8);
      gload16(gB1 + ko, nb + 4096 + t8);
    }
    v8h af[4], bf[2];
    #pragma unroll
    for (int i = 0; i < 4; ++i) af[i] = *(const v8h*)(bb + aoff[i]);
    #pragma unroll
    for (int j = 0; j < 2; ++j) bf[j] = *(const v8h*)(bb + boff[j]);
    #pragma unroll
    for (int i = 0; i < 4; ++i)
      #pragma unroll
      for (int j = 0; j < 2; ++j)
        acc[i][j] = __builtin_amdgcn_mfma_f32_16x16x32_f16(af[i], bf[j], acc[i][j], 0, 0, 0);
    if (tt + 2 < nt)      { WAITV3; }
    else if (tt + 1 < nt) { WAITV0; }
    __builtin_amdgcn_s_barrier();
    __builtin_amdgcn_sched_barrier(0);
    ++cur; if (cur >= 3) cur -= 3;
  }

  // epilogue: bias + 3-plane f16 split via LDS transpose [64][132] f32
  float* Ct = (float*)smem;
  __syncthreads();
  #pragma unroll
  for (int j = 0; j < 2; ++j) {
    const int colq = w * 32 + j * 16 + fr;       // 0..127
    const float bv = bias[n0 + colq];
    #pragma unroll
    for (int i = 0; i < 4; ++i)
      #pragma unroll
      for (int rr = 0; rr < 4; ++rr)
        Ct[(i * 16 + kg * 4 + rr) * 132 + colq] = acc[i][j][rr] + bv;
  }
  __syncthreads();
  const int r = t >> 2, cb = (t & 3) * 32;
  const int gcol = n0 + cb;
  const int ht = gcol >> 8, dd = gcol & 255;
  _Float16* p = Cq + (size_t)(m0 + r) * (3 * HALFD * NHT) + ht * (3 * HALFD) + dd;
  #pragma unroll
  for (int u = 0; u < 32; u += 8) {
    float vv[8];
    *(float4*)&vv[0] = *(const float4*)&Ct[r * 132 + cb + u];
    *(float4*)&vv[4] = *(const float4*)&Ct[r * 132 + cb + u + 4];
    v8h hv, dv, mv;
    #pragma unroll
    for (int e = 0; e < 8; ++e) {
      const _Float16 hh = (_Float16)vv[e];
      hv[e] = hh;
      mv[e] = (_Float16)((vv[e] - (float)hh) * 64.0f);
      dv[e] = (_Float16)((float)hh * 0.015625f);
    }
    *(v8h*)(p + u) = hv;                    // h
    *(v8h*)(p + HALFD + u) = dv;            // h/64
    *(v8h*)(p + 2 * HALFD + u) = mv;        // m
  }
}

// ========== GEMM2: S = Q'' @ keys''^T, 128x128 tile, BK=32, 3-buf ==========
__global__ __launch_bounds__(256) void gemm2_kernel(
    const _Float16* __restrict__ A, int lda, long aBS,
    const _Float16* __restrict__ B, int ldb, long bBS,
    float* __restrict__ Cf, int ldc, long cBS, int K) {
  __shared__ __align__(16) char smem[49152];   // 3 bufs x (A 8KB + B 8KB)
  _Float16* sh = (_Float16*)smem;
  const int t = threadIdx.x;
  const int z = blockIdx.z;
  const _Float16* Ab = A + (size_t)z * aBS;
  const _Float16* Bb = B + (size_t)z * bBS;
  const int m0 = blockIdx.y * 128, n0 = blockIdx.x * 128;

  const int o0 = t * 16;
  const int os = o0 ^ (((o0 >> 7) & 3) << 4);
  const int sr = os >> 6;
  const int sk = (os & 63) >> 1;
  const _Float16* gA0 = Ab + (size_t)(m0 + sr) * lda + sk;
  const _Float16* gA1 = Ab + (size_t)(m0 + sr + 64) * lda + sk;
  const _Float16* gB0 = Bb + (size_t)(n0 + sr) * ldb + sk;
  const _Float16* gB1 = Bb + (size_t)(n0 + sr + 64) * ldb + sk;
  const int t8 = t * 8;

  const int lane = t & 63, w = t >> 6;
  const int wr = (w >> 1) * 64, wc = (w & 1) * 64;
  const int fr = lane & 15, kg = lane >> 4;

  int aoff[4], boff[4];
  #pragma unroll
  for (int i = 0; i < 4; ++i) {
    const int ra = wr + i * 16 + fr;
    aoff[i] = (ra * 64 + ((kg ^ ((ra >> 1) & 3)) * 16)) >> 1;
    const int rb = wc + i * 16 + fr;
    boff[i] = ((rb * 64 + ((kg ^ ((rb >> 1) & 3)) * 16)) >> 1) + 4096;
  }

  v4f acc[4][4];
  #pragma unroll
  for (int i = 0; i < 4; ++i)
    #pragma unroll
    for (int j = 0; j < 4; ++j)
      acc[i][j] = (v4f){0.f, 0.f, 0.f, 0.f};

  const int nt = K >> 5;

  #pragma unroll
  for (int p = 0; p < 2; ++p) {
    _Float16* bb = sh + p * 8192;
    const size_t ko = (size_t)p * 32;
    gload16(gA0 + ko, bb + t8);
    gload16(gA1 + ko, bb + 2048 + t8);
    gload16(gB0 + ko, bb + 4096 + t8);
    gload16(gB1 + ko, bb + 6144 + t8);
  }
  WAITV4;
  __builtin_amdgcn_s_barrier();
  __builtin_amdgcn_sched_barrier(0);

  int cur = 0;
  for (int tt = 0; tt < nt; ++tt) {
    const _Float16* bb = sh + cur * 8192;
    if (tt + 2 < nt) {
      int sb = cur + 2; if (sb >= 3) sb -= 3;
      _Float16* nb = sh + sb * 8192;
      const size_t ko = (size_t)(tt + 2) * 32;
      gload16(gA0 + ko, nb + t8);
      gload16(gA1 + ko, nb + 2048 + t8);
      gload16(gB0 + ko, nb + 4096 + t8);
      gload16(gB1 + ko, nb + 6144 + t8);
    }
    v8h af[4], bf[4];
    #pragma unroll
    for (int i = 0; i < 4; ++i) af[i] = *(const v8h*)(bb + aoff[i]);
    #pragma unroll
    for (int j = 0; j < 4; ++j) bf[j] = *(const v8h*)(bb + boff[j]);
    #pragma unroll
    for (int i = 0; i < 4; ++i)
      #pragma unroll
      for (int j = 0; j < 4; ++j)
        acc[i][j] = __builtin_amdgcn_mfma_f32_16x16x32_f16(af[i], bf[j], acc[i][j], 0, 0, 0);
    if (tt + 2 < nt)      { WAITV4; }
    else if (tt + 1 < nt) { WAITV0; }
    __builtin_amdgcn_s_barrier();
    __builtin_amdgcn_sched_barrier(0);
    ++cur; if (cur >= 3) cur -= 3;
  }

  float* Cb = Cf + (size_t)z * cBS;
  #pragma unroll
  for (int i = 0; i < 4; ++i)
    #pragma unroll
    for (int j = 0; j < 4; ++j)
      #pragma unroll
      for (int rr = 0; rr < 4; ++rr) {
        const int rowg = m0 + wr + i * 16 + kg * 4 + rr;
        const int colg = n0 + wc + j * 16 + fr;
        Cb[(size_t)rowg * ldc + colg] = acc[i][j][rr];
      }
}

// ====== topk1 (x2) + cartesian-topk2 with FUSED gather, one block/token ======
// Round 0 of the cartesian loop always selects p=0 (row maxima + lowest-index
// tie rule) -> skip its shuffle chain and issue row-0 loads immediately.
__global__ __launch_bounds__(256) void topk_all_gather_kernel(
    const float* __restrict__ S, const float* __restrict__ values,
    float* __restrict__ out) {
  __shared__ float ls1[4][32], ls2[4][32];
  __shared__ int   li1[4][32], li2[4][32];
  __shared__ float red[4][1024];   // per-wave partial outputs (16 KB)
  const int b = blockIdx.x, t = threadIdx.x;
  const int lane = t & 63, h = t >> 6;
  const float* srA = S + ((size_t)b * NHT + 2 * h) * NKEYS;
  const float* srB = srA + NKEYS;
  float va[8], vb[8];
  #pragma unroll
  for (int j = 0; j < 8; ++j) va[j] = srA[j * 64 + lane];
  #pragma unroll
  for (int j = 0; j < 8; ++j) vb[j] = srB[j * 64 + lane];

  // ---- top-32 of row A (ht=2h) ----
  for (int r = 0; r < KNN; ++r) {
    float bv = -INFINITY; int bi = 0x7fffffff;
    #pragma unroll
    for (int j = 0; j < 8; ++j) {
      const int idx = j * 64 + lane;
      if (va[j] > bv) { bv = va[j]; bi = idx; }
    }
    #pragma unroll
    for (int off = 32; off > 0; off >>= 1) {
      const float ov = __shfl_xor(bv, off);
      const int oi = __shfl_xor(bi, off);
      if (ov > bv || (ov == bv && oi < bi)) { bv = ov; bi = oi; }
    }
    if (lane == 0) { ls1[h][r] = bv; li1[h][r] = bi; }
    const int jj = bi >> 6;
    const bool mine = (bi & 63) == lane;
    #pragma unroll
    for (int j = 0; j < 8; ++j)
      if (mine && j == jj) va[j] = -INFINITY;
  }
  // ---- top-32 of row B (ht=2h+1) ----
  for (int r = 0; r < KNN; ++r) {
    float bv = -INFINITY; int bi = 0x7fffffff;
    #pragma unroll
    for (int j = 0; j < 8; ++j) {
      const int idx = j * 64 + lane;
      if (vb[j] > bv) { bv = vb[j]; bi = idx; }
    }
    #pragma unroll
    for (int off = 32; off > 0; off >>= 1) {
      const float ov = __shfl_xor(bv, off);
      const int oi = __shfl_xor(bi, off);
      if (ov > bv || (ov == bv && oi < bi)) { bv = ov; bi = oi; }
    }
    if (lane == 0) { ls2[h][r] = bv; li2[h][r] = bi; }
    const int jj = bi >> 6;
    const bool mine = (bi & 63) == lane;
    #pragma unroll
    for (int j = 0; j < 8; ++j)
      if (mine && j == jj) vb[j] = -INFINITY;
  }

  // ---- cartesian top-32 with fused weighted gather ----
  float v[16];
  #pragma unroll
  for (int c = 0; c < 16; ++c) {
    const int p = c * 64 + lane;
    v[c] = ls1[h][p >> 5] + ls2[h][p & 31];
  }
  float4 acc0 = {0,0,0,0}, acc1 = {0,0,0,0}, acc2 = {0,0,0,0}, acc3 = {0,0,0,0};
  float4 pv0, pv1, pv2, pv3;
  // round 0 shortcut: p=0 always wins (bit-identical to the shuffle chain)
  const float m = ls1[h][0] + ls2[h][0];
  float Z = 1.0f;          // expf(m - m)
  float pe = 1.0f;
  {
    const int row0 = li1[h][0] * NKEYS + li2[h][0];
    const float4* vp = (const float4*)(values + (size_t)row0 * VDIM) + lane;
    pv0 = vp[0]; pv1 = vp[64]; pv2 = vp[128]; pv3 = vp[192];
    if (lane == 0) v[0] = -INFINITY;   // removal of p=0
  }
  for (int r = 1; r < KNN; ++r) {
    float bv = -INFINITY; int bp = 0x7fffffff;
    #pragma unroll
    for (int c = 0; c < 16; ++c) {
      const int p = c * 64 + lane;
      if (v[c] > bv) { bv = v[c]; bp = p; }
    }
    #pragma unroll
    for (int off = 32; off > 0; off >>= 1) {
      const float ov = __shfl_xor(bv, off);
      const int op = __shfl_xor(bp, off);
      if (ov > bv || (ov == bv && op < bp)) { bv = ov; bp = op; }
    }
    const int row = li1[h][bp >> 5] * NKEYS + li2[h][bp & 31];
    const float e = expf(bv - m);
    Z += e;
    const float4* vp = (const float4*)(values + (size_t)row * VDIM) + lane;
    const float4 c0 = vp[0], c1 = vp[64], c2 = vp[128], c3 = vp[192];
    acc0.x = fmaf(pe, pv0.x, acc0.x); acc0.y = fmaf(pe, pv0.y, acc0.y);
    acc0.z = fmaf(pe, pv0.z, acc0.z); acc0.w = fmaf(pe, pv0.w, acc0.w);
    acc1.x = fmaf(pe, pv1.x, acc1.x); acc1.y = fmaf(pe, pv1.y, acc1.y);
    acc1.z = fmaf(pe, pv1.z, acc1.z); acc1.w = fmaf(pe, pv1.w, acc1.w);
    acc2.x = fmaf(pe, pv2.x, acc2.x); acc2.y = fmaf(pe, pv2.y, acc2.y);
    acc2.z = fmaf(pe, pv2.z, acc2.z); acc2.w = fmaf(pe, pv2.w, acc2.w);
    acc3.x = fmaf(pe, pv3.x, acc3.x); acc3.y = fmaf(pe, pv3.y, acc3.y);
    acc3.z = fmaf(pe, pv3.z, acc3.z); acc3.w = fmaf(pe, pv3.w, acc3.w);
    pv0 = c0; pv1 = c1; pv2 = c2; pv3 = c3; pe = e;
    const int cc = bp >> 6;
    const bool mine = (bp & 63) == lane;
    #pragma unroll
    for (int c = 0; c < 16; ++c)
      if (mine && c == cc) v[c] = -INFINITY;
  }
  const float invZ = 1.0f / Z;
  acc0.x = fmaf(pe, pv0.x, acc0.x); acc0.y = fmaf(pe, pv0.y, acc0.y);
  acc0.z = fmaf(pe, pv0.z, acc0.z); acc0.w = fmaf(pe, pv0.w, acc0.w);
  acc1.x = fmaf(pe, pv1.x, acc1.x); acc1.y = fmaf(pe, pv1.y, acc1.y);
  acc1.z = fmaf(pe, pv1.z, acc1.z); acc1.w = fmaf(pe, pv1.w, acc1.w);
  acc2.x = fmaf(pe, pv2.x, acc2.x); acc2.y = fmaf(pe, pv2.y, acc2.y);
  acc2.z = fmaf(pe, pv2.z, acc2.z); acc2.w = fmaf(pe, pv2.w, acc2.w);
  acc3.x = fmaf(pe, pv3.x, acc3.x); acc3.y = fmaf(pe, pv3.y, acc3.y);
  acc3.z = fmaf(pe, pv3.z, acc3.z); acc3.w = fmaf(pe, pv3.w, acc3.w);
  acc0.x *= invZ; acc0.y *= invZ; acc0.z *= invZ; acc0.w *= invZ;
  acc1.x *= invZ; acc1.y *= invZ; acc1.z *= invZ; acc1.w *= invZ;
  acc2.x *= invZ; acc2.y *= invZ; acc2.z *= invZ; acc2.w *= invZ;
  acc3.x *= invZ; acc3.y *= invZ; acc3.z *= invZ; acc3.w *= invZ;

  float4* rp = (float4*)&red[h][0];
  rp[lane] = acc0; rp[lane + 64] = acc1; rp[lane + 128] = acc2; rp[lane + 192] = acc3;
  __syncthreads();
  const float4* r0 = (const float4*)&red[0][0];
  const float4* r1 = (const float4*)&red[1][0];
  const float4* r2 = (const float4*)&red[2][0];
  const float4* r3 = (const float4*)&red[3][0];
  float4 o;
  o.x = r0[t].x + r1[t].x + r2[t].x + r3[t].x;
  o.y = r0[t].y + r1[t].y + r2[t].y + r3[t].y;
  o.z = r0[t].z + r1[t].z + r2[t].z + r3[t].z;
  o.w = r0[t].w + r1[t].w + r2[t].w + r3[t].w;
  ((float4*)&out[(size_t)b * VDIM])[t] = o;
}

extern "C" void kernel_launch(void* const* d_in, const int* in_sizes, int n_in,
                              void* d_out, int out_size, void* d_ws, size_t ws_size,
                              hipStream_t stream) {
  const float* x      = (const float*)d_in[0];
  const float* w_q    = (const float*)d_in[1];
  const float* b_q    = (const float*)d_in[2];
  const float* keys   = (const float*)d_in[3];
  const float* values = (const float*)d_in[4];
  float* out = (float*)d_out;

  char* ws = (char*)d_ws;
  _Float16* xs    = (_Float16*)(ws);                  // 2048*3072*2 = 12.6 MB
  _Float16* wqs   = (_Float16*)(ws + (16u  << 20));   // 12.6 MB
  _Float16* keyss = (_Float16*)(ws + (32u  << 20));   // 4096*768*2 = 6.3 MB
  _Float16* Qs    = (_Float16*)(ws + (40u  << 20));   // 2048*6144*2 = 25.2 MB
  float*    S     = (float*)   (ws + (68u  << 20));   // 2048*4096*4 = 32 MB

  split_all_kernel<<<5120, 256, 0, stream>>>(x, w_q, keys, xs, wqs, keyss);

  // GEMM1: M=2048(x64 tiles), N=2048(x128 tiles), K'=3072 -> grid 512, 2 blocks/CU
  gemm1_kernel<<<dim3(QDIM / 128, BSZ / 64), 256, 0, stream>>>(xs, wqs, b_q, Qs);
  // GEMM2: 8 x (M=2048, N=512, K'=768) -> grid 512
  gemm2_kernel<<<dim3(NKEYS / 128, BSZ / 128, NHT), 256, 0, stream>>>(
      Qs, 3 * HALFD * NHT, 3 * HALFD, keyss, 3 * HALFD, (long)NKEYS * 3 * HALFD,
      S, NHT * NKEYS, NKEYS, 3 * HALFD);

  topk_all_gather_kernel<<<BSZ, 256, 0, stream>>>(S, values, out);
}

// Round 13
// 347.073 us; speedup vs baseline: 1.0156x; 1.0156x over previous
//
#include <hip/hip_runtime.h>
#include <math.h>

#define BSZ   2048
#define INDIM 1024
#define QDIM  2048   // HEADS*K_DIM
#define NHT   8      // HEADS*2
#define NKEYS 512
#define HALFD 256
#define KNN   32
#define VDIM  1024
#define HEADS 4

typedef _Float16 v8h __attribute__((ext_vector_type(8)));
typedef _Float16 v4h __attribute__((ext_vector_type(4)));
typedef float    v4f __attribute__((ext_vector_type(4)));

// ---------- f32 -> {h, h/64, m=64*(a-h)} f16 plane split ----------
// A-side plane order: [h, h/64, m]; B-side: [h, m, h/64]
template<int KSHIFT, bool ASIDE>
__device__ __forceinline__ void split4(const float* __restrict__ in,
                                       _Float16* __restrict__ out, int i) {
  const long e0 = (long)i * 4;
  const int K = 1 << KSHIFT;
  const long r = e0 >> KSHIFT;
  const int k = (int)(e0 & (K - 1));
  const float4 a = *(const float4*)&in[e0];
  const float av[4] = {a.x, a.y, a.z, a.w};
  v4h hv, dv, mv;
  #pragma unroll
  for (int u = 0; u < 4; ++u) {
    const _Float16 hh = (_Float16)av[u];
    hv[u] = hh;
    mv[u] = (_Float16)((av[u] - (float)hh) * 64.0f);
    dv[u] = (_Float16)((float)hh * 0.015625f);
  }
  _Float16* base = out + r * (3L * K) + k;
  *(v4h*)(base)         = hv;
  *(v4h*)(base + K)     = ASIDE ? dv : mv;
  *(v4h*)(base + 2 * K) = ASIDE ? mv : dv;
}

__global__ __launch_bounds__(256) void split_all_kernel(
    const float* __restrict__ x, const float* __restrict__ wq, const float* __restrict__ ky,
    _Float16* __restrict__ xs, _Float16* __restrict__ wqs, _Float16* __restrict__ kys) {
  const int i = blockIdx.x * 256 + threadIdx.x;
  if (i < 524288)            split4<10, true >(x,  xs,  i);
  else if (i < 1048576)      split4<10, false>(wq, wqs, i - 524288);
  else                       split4<8,  false>(ky, kys, i - 1048576);
}

// ---------- async global->LDS 16B ----------
__device__ __forceinline__ void gload16(const _Float16* g, _Float16* l) {
  __builtin_amdgcn_global_load_lds(
      (const __attribute__((address_space(1))) unsigned int*)g,
      (__attribute__((address_space(3))) unsigned int*)l, 16, 0, 0);
}

#define WAITV8 asm volatile("s_waitcnt vmcnt(8)" ::: "memory")
#define WAITV4 asm volatile("s_waitcnt vmcnt(4)" ::: "memory")
#define WAITV0 asm volatile("s_waitcnt vmcnt(0)" ::: "memory")

// ---------- f16 MFMA GEMM, 128x128 tile, BK=32, 4-buffer 3-ahead pipeline ----------
// 64 KB LDS -> 2 blocks/CU. Counted vmcnt across raw barriers (R7/R8-proven).
// Q_EPI: bias + 3-plane f16 epilogue (LDS-transposed, vectorized stores).
template<bool Q_EPI>
__global__ __launch_bounds__(256) void mfma_gemm(
    const _Float16* __restrict__ A, int lda, long aBS,
    const _Float16* __restrict__ B, int ldb, long bBS,
    const float* __restrict__ bias,
    float* __restrict__ Cf, int ldc, long cBS,
    _Float16* __restrict__ Cq, int K) {
  __shared__ __align__(16) char smem[65536];   // 4 bufs x (A 8KB + B 8KB)
  _Float16* sh = (_Float16*)smem;
  const int t = threadIdx.x;
  const int z = blockIdx.z;
  const _Float16* Ab = A + (size_t)z * aBS;
  const _Float16* Bb = B + (size_t)z * bBS;
  const int m0 = blockIdx.y * 128, n0 = blockIdx.x * 128;

  // staging: LDS dest linear; global source inverse-swizzled
  // swizzle: byte ^= ((byte>>7)&3)<<4
  const int o0 = t * 16;
  const int os = o0 ^ (((o0 >> 7) & 3) << 4);
  const int sr = os >> 6;            // source row within 64-row half
  const int sk = (os & 63) >> 1;     // source k element (0..31)
  const _Float16* gA0 = Ab + (size_t)(m0 + sr) * lda + sk;
  const _Float16* gA1 = Ab + (size_t)(m0 + sr + 64) * lda + sk;
  const _Float16* gB0 = Bb + (size_t)(n0 + sr) * ldb + sk;
  const _Float16* gB1 = Bb + (size_t)(n0 + sr + 64) * ldb + sk;
  const int t8 = t * 8;

  const int lane = t & 63, w = t >> 6;
  const int wr = (w >> 1) * 64, wc = (w & 1) * 64;
  const int fr = lane & 15, kg = lane >> 4;

  int aoff[4], boff[4];
  #pragma unroll
  for (int i = 0; i < 4; ++i) {
    const int ra = wr + i * 16 + fr;
    aoff[i] = (ra * 64 + ((kg ^ ((ra >> 1) & 3)) * 16)) >> 1;
    const int rb = wc + i * 16 + fr;
    boff[i] = ((rb * 64 + ((kg ^ ((rb >> 1) & 3)) * 16)) >> 1) + 4096;
  }

  v4f acc[4][4];
  #pragma unroll
  for (int i = 0; i < 4; ++i)
    #pragma unroll
    for (int j = 0; j < 4; ++j)
      acc[i][j] = (v4f){0.f, 0.f, 0.f, 0.f};

  const int nt = K >> 5;   // BK=32 tiles

  // prologue: stage tiles 0..2 into bufs 0..2 (12 loads in flight)
  #pragma unroll
  for (int p = 0; p < 3; ++p) {
    _Float16* bb = sh + p * 8192;
    const size_t ko = (size_t)p * 32;
    gload16(gA0 + ko, bb + t8);
    gload16(gA1 + ko, bb + 2048 + t8);
    gload16(gB0 + ko, bb + 4096 + t8);
    gload16(gB1 + ko, bb + 6144 + t8);
  }
  WAITV8;                              // tile 0 landed (all waves)
  __builtin_amdgcn_s_barrier();
  __builtin_amdgcn_sched_barrier(0);

  for (int tt = 0; tt < nt; ++tt) {
    const _Float16* bb = sh + (tt & 3) * 8192;
    if (tt + 3 < nt) {                 // stage tile tt+3
      _Float16* nb = sh + ((tt + 3) & 3) * 8192;
      const size_t ko = (size_t)(tt + 3) * 32;
      gload16(gA0 + ko, nb + t8);
      gload16(gA1 + ko, nb + 2048 + t8);
      gload16(gB0 + ko, nb + 4096 + t8);
      gload16(gB1 + ko, nb + 6144 + t8);
    }
    v8h af[4], bf[4];
    #pragma unroll
    for (int i = 0; i < 4; ++i) af[i] = *(const v8h*)(bb + aoff[i]);
    #pragma unroll
    for (int j = 0; j < 4; ++j) bf[j] = *(const v8h*)(bb + boff[j]);
    #pragma unroll
    for (int i = 0; i < 4; ++i)
      #pragma unroll
      for (int j = 0; j < 4; ++j)
        acc[i][j] = __builtin_amdgcn_mfma_f32_16x16x32_f16(af[i], bf[j], acc[i][j], 0, 0, 0);
    if (tt + 3 < nt)      { WAITV8; }
    else if (tt + 2 < nt) { WAITV4; }
    else if (tt + 1 < nt) { WAITV0; }
    __builtin_amdgcn_s_barrier();
    __builtin_amdgcn_sched_barrier(0);
  }

  // C/D map (16x16x32): col = lane&15, row = (lane>>4)*4 + reg
  if (Q_EPI) {
    float* Ct = (float*)smem;
    #pragma unroll
    for (int half = 0; half < 2; ++half) {
      __syncthreads();
      if ((w & 1) == half) {
        #pragma unroll
        for (int j = 0; j < 4; ++j) {
          const int colq = j * 16 + fr;
          const float bv = bias[n0 + half * 64 + colq];
          #pragma unroll
          for (int i = 0; i < 4; ++i)
            #pragma unroll
            for (int rr = 0; rr < 4; ++rr)
              Ct[(wr + i * 16 + kg * 4 + rr) * 68 + colq] = acc[i][j][rr] + bv;
        }
      }
      __syncthreads();
      const int r = t >> 1, cb = (t & 1) * 32;
      const int gcol = n0 + half * 64 + cb;
      const int ht = gcol >> 8, dd = gcol & 255;
      _Float16* p = Cq + (size_t)(m0 + r) * (3 * HALFD * NHT) + ht * (3 * HALFD) + dd;
      #pragma unroll
      for (int u = 0; u < 32; u += 8) {
        float vv[8];
        *(float4*)&vv[0] = *(const float4*)&Ct[r * 68 + cb + u];
        *(float4*)&vv[4] = *(const float4*)&Ct[r * 68 + cb + u + 4];
        v8h hv, dv, mv;
        #pragma unroll
        for (int e = 0; e < 8; ++e) {
          const _Float16 hh = (_Float16)vv[e];
          hv[e] = hh;
          mv[e] = (_Float16)((vv[e] - (float)hh) * 64.0f);
          dv[e] = (_Float16)((float)hh * 0.015625f);
        }
        *(v8h*)(p + u) = hv;                    // h
        *(v8h*)(p + HALFD + u) = dv;            // h/64
        *(v8h*)(p + 2 * HALFD + u) = mv;        // m
      }
    }
  } else {
    float* Cb = Cf + (size_t)z * cBS;
    #pragma unroll
    for (int i = 0; i < 4; ++i)
      #pragma unroll
      for (int j = 0; j < 4; ++j)
        #pragma unroll
        for (int rr = 0; rr < 4; ++rr) {
          const int rowg = m0 + wr + i * 16 + kg * 4 + rr;
          const int colg = n0 + wc + j * 16 + fr;
          Cb[(size_t)rowg * ldc + colg] = acc[i][j][rr];
        }
  }
}

// ====== topk1 (x2) + cartesian-topk2 with FUSED gather, one block/token ======
// Round 0 of the cartesian loop always selects p=0 (row maxima + lowest-index
// tie rule) -> skip its shuffle chain and issue row-0 loads immediately.
__global__ __launch_bounds__(256) void topk_all_gather_kernel(
    const float* __restrict__ S, const float* __restrict__ values,
    float* __restrict__ out) {
  __shared__ float ls1[4][32], ls2[4][32];
  __shared__ int   li1[4][32], li2[4][32];
  __shared__ float red[4][1024];   // per-wave partial outputs (16 KB)
  const int b = blockIdx.x, t = threadIdx.x;
  const int lane = t & 63, h = t >> 6;
  const float* srA = S + ((size_t)b * NHT + 2 * h) * NKEYS;
  const float* srB = srA + NKEYS;
  float va[8], vb[8];
  #pragma unroll
  for (int j = 0; j < 8; ++j) va[j] = srA[j * 64 + lane];
  #pragma unroll
  for (int j = 0; j < 8; ++j) vb[j] = srB[j * 64 + lane];

  // ---- top-32 of row A (ht=2h) ----
  for (int r = 0; r < KNN; ++r) {
    float bv = -INFINITY; int bi = 0x7fffffff;
    #pragma unroll
    for (int j = 0; j < 8; ++j) {
      const int idx = j * 64 + lane;
      if (va[j] > bv) { bv = va[j]; bi = idx; }
    }
    #pragma unroll
    for (int off = 32; off > 0; off >>= 1) {
      const float ov = __shfl_xor(bv, off);
      const int oi = __shfl_xor(bi, off);
      if (ov > bv || (ov == bv && oi < bi)) { bv = ov; bi = oi; }
    }
    if (lane == 0) { ls1[h][r] = bv; li1[h][r] = bi; }
    const int jj = bi >> 6;
    const bool mine = (bi & 63) == lane;
    #pragma unroll
    for (int j = 0; j < 8; ++j)
      if (mine && j == jj) va[j] = -INFINITY;
  }
  // ---- top-32 of row B (ht=2h+1) ----
  for (int r = 0; r < KNN; ++r) {
    float bv = -INFINITY; int bi = 0x7fffffff;
    #pragma unroll
    for (int j = 0; j < 8; ++j) {
      const int idx = j * 64 + lane;
      if (vb[j] > bv) { bv = vb[j]; bi = idx; }
    }
    #pragma unroll
    for (int off = 32; off > 0; off >>= 1) {
      const float ov = __shfl_xor(bv, off);
      const int oi = __shfl_xor(bi, off);
      if (ov > bv || (ov == bv && oi < bi)) { bv = ov; bi = oi; }
    }
    if (lane == 0) { ls2[h][r] = bv; li2[h][r] = bi; }
    const int jj = bi >> 6;
    const bool mine = (bi & 63) == lane;
    #pragma unroll
    for (int j = 0; j < 8; ++j)
      if (mine && j == jj) vb[j] = -INFINITY;
  }

  // ---- cartesian top-32 with fused weighted gather ----
  float v[16];
  #pragma unroll
  for (int c = 0; c < 16; ++c) {
    const int p = c * 64 + lane;
    v[c] = ls1[h][p >> 5] + ls2[h][p & 31];
  }
  float4 acc0 = {0,0,0,0}, acc1 = {0,0,0,0}, acc2 = {0,0,0,0}, acc3 = {0,0,0,0};
  float4 pv0, pv1, pv2, pv3;
  // round 0 shortcut: p=0 always wins (bit-identical to the shuffle chain)
  const float m = ls1[h][0] + ls2[h][0];
  float Z = 1.0f;          // expf(m - m)
  float pe = 1.0f;
  {
    const int row0 = li1[h][0] * NKEYS + li2[h][0];
    const float4* vp = (const float4*)(values + (size_t)row0 * VDIM) + lane;
    pv0 = vp[0]; pv1 = vp[64]; pv2 = vp[128]; pv3 = vp[192];
    if (lane == 0) v[0] = -INFINITY;   // removal of p=0
  }
  for (int r = 1; r < KNN; ++r) {
    float bv = -INFINITY; int bp = 0x7fffffff;
    #pragma unroll
    for (int c = 0; c < 16; ++c) {
      const int p = c * 64 + lane;
      if (v[c] > bv) { bv = v[c]; bp = p; }
    }
    #pragma unroll
    for (int off = 32; off > 0; off >>= 1) {
      const float ov = __shfl_xor(bv, off);
      const int op = __shfl_xor(bp, off);
      if (ov > bv || (ov == bv && op < bp)) { bv = ov; bp = op; }
    }
    const int row = li1[h][bp >> 5] * NKEYS + li2[h][bp & 31];
    const float e = expf(bv - m);
    Z += e;
    const float4* vp = (const float4*)(values + (size_t)row * VDIM) + lane;
    const float4 c0 = vp[0], c1 = vp[64], c2 = vp[128], c3 = vp[192];
    acc0.x = fmaf(pe, pv0.x, acc0.x); acc0.y = fmaf(pe, pv0.y, acc0.y);
    acc0.z = fmaf(pe, pv0.z, acc0.z); acc0.w = fmaf(pe, pv0.w, acc0.w);
    acc1.x = fmaf(pe, pv1.x, acc1.x); acc1.y = fmaf(pe, pv1.y, acc1.y);
    acc1.z = fmaf(pe, pv1.z, acc1.z); acc1.w = fmaf(pe, pv1.w, acc1.w);
    acc2.x = fmaf(pe, pv2.x, acc2.x); acc2.y = fmaf(pe, pv2.y, acc2.y);
    acc2.z = fmaf(pe, pv2.z, acc2.z); acc2.w = fmaf(pe, pv2.w, acc2.w);
    acc3.x = fmaf(pe, pv3.x, acc3.x); acc3.y = fmaf(pe, pv3.y, acc3.y);
    acc3.z = fmaf(pe, pv3.z, acc3.z); acc3.w = fmaf(pe, pv3.w, acc3.w);
    pv0 = c0; pv1 = c1; pv2 = c2; pv3 = c3; pe = e;
    const int cc = bp >> 6;
    const bool mine = (bp & 63) == lane;
    #pragma unroll
    for (int c = 0; c < 16; ++c)
      if (mine && c == cc) v[c] = -INFINITY;
  }
  const float invZ = 1.0f / Z;
  acc0.x = fmaf(pe, pv0.x, acc0.x); acc0.y = fmaf(pe, pv0.y, acc0.y);
  acc0.z = fmaf(pe, pv0.z, acc0.z); acc0.w = fmaf(pe, pv0.w, acc0.w);
  acc1.x = fmaf(pe, pv1.x, acc1.x); acc1.y = fmaf(pe, pv1.y, acc1.y);
  acc1.z = fmaf(pe, pv1.z, acc1.z); acc1.w = fmaf(pe, pv1.w, acc1.w);
  acc2.x = fmaf(pe, pv2.x, acc2.x); acc2.y = fmaf(pe, pv2.y, acc2.y);
  acc2.z = fmaf(pe, pv2.z, acc2.z); acc2.w = fmaf(pe, pv2.w, acc2.w);
  acc3.x = fmaf(pe, pv3.x, acc3.x); acc3.y = fmaf(pe, pv3.y, acc3.y);
  acc3.z = fmaf(pe, pv3.z, acc3.z); acc3.w = fmaf(pe, pv3.w, acc3.w);
  acc0.x *= invZ; acc0.y *= invZ; acc0.z *= invZ; acc0.w *= invZ;
  acc1.x *= invZ; acc1.y *= invZ; acc1.z *= invZ; acc1.w *= invZ;
  acc2.x *= invZ; acc2.y *= invZ; acc2.z *= invZ; acc2.w *= invZ;
  acc3.x *= invZ; acc3.y *= invZ; acc3.z *= invZ; acc3.w *= invZ;

  float4* rp = (float4*)&red[h][0];
  rp[lane] = acc0; rp[lane + 64] = acc1; rp[lane + 128] = acc2; rp[lane + 192] = acc3;
  __syncthreads();
  const float4* r0 = (const float4*)&red[0][0];
  const float4* r1 = (const float4*)&red[1][0];
  const float4* r2 = (const float4*)&red[2][0];
  const float4* r3 = (const float4*)&red[3][0];
  float4 o;
  o.x = r0[t].x + r1[t].x + r2[t].x + r3[t].x;
  o.y = r0[t].y + r1[t].y + r2[t].y + r3[t].y;
  o.z = r0[t].z + r1[t].z + r2[t].z + r3[t].z;
  o.w = r0[t].w + r1[t].w + r2[t].w + r3[t].w;
  ((float4*)&out[(size_t)b * VDIM])[t] = o;
}

extern "C" void kernel_launch(void* const* d_in, const int* in_sizes, int n_in,
                              void* d_out, int out_size, void* d_ws, size_t ws_size,
                              hipStream_t stream) {
  const float* x      = (const float*)d_in[0];
  const float* w_q    = (const float*)d_in[1];
  const float* b_q    = (const float*)d_in[2];
  const float* keys   = (const float*)d_in[3];
  const float* values = (const float*)d_in[4];
  float* out = (float*)d_out;

  char* ws = (char*)d_ws;
  _Float16* xs    = (_Float16*)(ws);                  // 2048*3072*2 = 12.6 MB
  _Float16* wqs   = (_Float16*)(ws + (16u  << 20));   // 12.6 MB
  _Float16* keyss = (_Float16*)(ws + (32u  << 20));   // 4096*768*2 = 6.3 MB
  _Float16* Qs    = (_Float16*)(ws + (40u  << 20));   // 2048*6144*2 = 25.2 MB
  float*    S     = (float*)   (ws + (68u  << 20));   // 2048*4096*4 = 32 MB

  split_all_kernel<<<5120, 256, 0, stream>>>(x, w_q, keys, xs, wqs, keyss);

  // GEMM1: Q'' = split(x'' @ w_q''^T + b) : M=2048, N=2048, K'=3072 (2 blocks/CU)
  mfma_gemm<true><<<dim3(QDIM / 128, BSZ / 128, 1), 256, 0, stream>>>(
      xs, 3 * INDIM, 0, wqs, 3 * INDIM, 0, b_q,
      nullptr, 0, 0, Qs, 3 * INDIM);
  // GEMM2: S = Q'' @ keys''^T : 8 x (M=2048, N=512, K'=768)
  mfma_gemm<false><<<dim3(NKEYS / 128, BSZ / 128, NHT), 256, 0, stream>>>(
      Qs, 3 * HALFD * NHT, 3 * HALFD, keyss, 3 * HALFD, (long)NKEYS * 3 * HALFD, nullptr,
      S, NHT * NKEYS, NKEYS, nullptr, 3 * HALFD);

  topk_all_gather_kernel<<<BSZ, 256, 0, stream>>>(S, values, out);
}

// Round 14
// 333.644 us; speedup vs baseline: 1.0564x; 1.0402x over previous
//
#include <hip/hip_runtime.h>
#include <math.h>

#define BSZ   2048
#define INDIM 1024
#define QDIM  2048   // HEADS*K_DIM
#define NHT   8      // HEADS*2
#define NKEYS 512
#define HALFD 256
#define KNN   32
#define VDIM  1024
#define HEADS 4

typedef _Float16 v8h __attribute__((ext_vector_type(8)));
typedef _Float16 v4h __attribute__((ext_vector_type(4)));
typedef float    v4f __attribute__((ext_vector_type(4)));

// ---------- f32 -> {h, h/64, m=64*(a-h)} f16 plane split ----------
// A-side plane order: [h, h/64, m]; B-side: [h, m, h/64]
template<int KSHIFT, bool ASIDE>
__device__ __forceinline__ void split4(const float* __restrict__ in,
                                       _Float16* __restrict__ out, int i) {
  const long e0 = (long)i * 4;
  const int K = 1 << KSHIFT;
  const long r = e0 >> KSHIFT;
  const int k = (int)(e0 & (K - 1));
  const float4 a = *(const float4*)&in[e0];
  const float av[4] = {a.x, a.y, a.z, a.w};
  v4h hv, dv, mv;
  #pragma unroll
  for (int u = 0; u < 4; ++u) {
    const _Float16 hh = (_Float16)av[u];
    hv[u] = hh;
    mv[u] = (_Float16)((av[u] - (float)hh) * 64.0f);
    dv[u] = (_Float16)((float)hh * 0.015625f);
  }
  _Float16* base = out + r * (3L * K) + k;
  *(v4h*)(base)         = hv;
  *(v4h*)(base + K)     = ASIDE ? dv : mv;
  *(v4h*)(base + 2 * K) = ASIDE ? mv : dv;
}

__global__ __launch_bounds__(256) void split_all_kernel(
    const float* __restrict__ x, const float* __restrict__ wq, const float* __restrict__ ky,
    _Float16* __restrict__ xs, _Float16* __restrict__ wqs, _Float16* __restrict__ kys) {
  const int i = blockIdx.x * 256 + threadIdx.x;
  if (i < 524288)            split4<10, true >(x,  xs,  i);
  else if (i < 1048576)      split4<10, false>(wq, wqs, i - 524288);
  else                       split4<8,  false>(ky, kys, i - 1048576);
}

// ---------- async global->LDS 16B ----------
__device__ __forceinline__ void gload16(const _Float16* g, _Float16* l) {
  __builtin_amdgcn_global_load_lds(
      (const __attribute__((address_space(1))) unsigned int*)g,
      (__attribute__((address_space(3))) unsigned int*)l, 16, 0, 0);
}

#define WAITV8 asm volatile("s_waitcnt vmcnt(8)" ::: "memory")
#define WAITV4 asm volatile("s_waitcnt vmcnt(4)" ::: "memory")
#define WAITV0 asm volatile("s_waitcnt vmcnt(0)" ::: "memory")

// ---------- f16 MFMA GEMM, 128x128 tile, BK=32, 4-buffer 3-ahead pipeline ----------
// Counted vmcnt across raw barriers: loads for tiles t+2,t+3 stay in flight.
// Q_EPI: bias + 3-plane f16 epilogue (LDS-transposed, vectorized stores).
template<bool Q_EPI>
__global__ __launch_bounds__(256) void mfma_gemm(
    const _Float16* __restrict__ A, int lda, long aBS,
    const _Float16* __restrict__ B, int ldb, long bBS,
    const float* __restrict__ bias,
    float* __restrict__ Cf, int ldc, long cBS,
    _Float16* __restrict__ Cq, int K) {
  __shared__ __align__(16) char smem[65536];   // 4 bufs x (A 8KB + B 8KB)
  _Float16* sh = (_Float16*)smem;
  const int t = threadIdx.x;
  const int z = blockIdx.z;
  const _Float16* Ab = A + (size_t)z * aBS;
  const _Float16* Bb = B + (size_t)z * bBS;
  const int m0 = blockIdx.y * 128, n0 = blockIdx.x * 128;

  // staging: LDS dest linear; global source inverse-swizzled
  // swizzle: byte ^= ((byte>>7)&3)<<4
  const int o0 = t * 16;
  const int os = o0 ^ (((o0 >> 7) & 3) << 4);
  const int sr = os >> 6;            // source row within 64-row half
  const int sk = (os & 63) >> 1;     // source k element (0..31)
  const _Float16* gA0 = Ab + (size_t)(m0 + sr) * lda + sk;
  const _Float16* gA1 = Ab + (size_t)(m0 + sr + 64) * lda + sk;
  const _Float16* gB0 = Bb + (size_t)(n0 + sr) * ldb + sk;
  const _Float16* gB1 = Bb + (size_t)(n0 + sr + 64) * ldb + sk;
  const int t8 = t * 8;

  const int lane = t & 63, w = t >> 6;
  const int wr = (w >> 1) * 64, wc = (w & 1) * 64;
  const int fr = lane & 15, kg = lane >> 4;

  int aoff[4], boff[4];
  #pragma unroll
  for (int i = 0; i < 4; ++i) {
    const int ra = wr + i * 16 + fr;
    aoff[i] = (ra * 64 + ((kg ^ ((ra >> 1) & 3)) * 16)) >> 1;
    const int rb = wc + i * 16 + fr;
    boff[i] = ((rb * 64 + ((kg ^ ((rb >> 1) & 3)) * 16)) >> 1) + 4096;
  }

  v4f acc[4][4];
  #pragma unroll
  for (int i = 0; i < 4; ++i)
    #pragma unroll
    for (int j = 0; j < 4; ++j)
      acc[i][j] = (v4f){0.f, 0.f, 0.f, 0.f};

  const int nt = K >> 5;   // BK=32 tiles; nt >= 4 for all our shapes

  // prologue: stage tiles 0..2 into bufs 0..2 (12 loads in flight)
  #pragma unroll
  for (int p = 0; p < 3; ++p) {
    _Float16* bb = sh + p * 8192;
    const size_t ko = (size_t)p * 32;
    gload16(gA0 + ko, bb + t8);
    gload16(gA1 + ko, bb + 2048 + t8);
    gload16(gB0 + ko, bb + 4096 + t8);
    gload16(gB1 + ko, bb + 6144 + t8);
  }
  WAITV8;                              // tile 0 landed (all waves)
  __builtin_amdgcn_s_barrier();
  __builtin_amdgcn_sched_barrier(0);

  for (int tt = 0; tt < nt; ++tt) {
    const _Float16* bb = sh + (tt & 3) * 8192;
    if (tt + 3 < nt) {                 // stage tile tt+3 (overwrites buf read at tt-1)
      _Float16* nb = sh + ((tt + 3) & 3) * 8192;
      const size_t ko = (size_t)(tt + 3) * 32;
      gload16(gA0 + ko, nb + t8);
      gload16(gA1 + ko, nb + 2048 + t8);
      gload16(gB0 + ko, nb + 4096 + t8);
      gload16(gB1 + ko, nb + 6144 + t8);
    }
    v8h af[4], bf[4];
    #pragma unroll
    for (int i = 0; i < 4; ++i) af[i] = *(const v8h*)(bb + aoff[i]);
    #pragma unroll
    for (int j = 0; j < 4; ++j) bf[j] = *(const v8h*)(bb + boff[j]);
    #pragma unroll
    for (int i = 0; i < 4; ++i)
      #pragma unroll
      for (int j = 0; j < 4; ++j)
        acc[i][j] = __builtin_amdgcn_mfma_f32_16x16x32_f16(af[i], bf[j], acc[i][j], 0, 0, 0);
    // counted wait: tile tt+1 landed for THIS wave; barrier makes it true for ALL waves
    if (tt + 3 < nt)      { WAITV8; }
    else if (tt + 2 < nt) { WAITV4; }
    else if (tt + 1 < nt) { WAITV0; }
    __builtin_amdgcn_s_barrier();
    __builtin_amdgcn_sched_barrier(0);   // pin next iter's ds_reads after barrier
  }

  // C/D map (16x16x32): col = lane&15, row = (lane>>4)*4 + reg
  if (Q_EPI) {
    // two 64-col passes through LDS [128][68] f32 (34816 B <= 64KB)
    float* Ct = (float*)smem;
    #pragma unroll
    for (int half = 0; half < 2; ++half) {
      __syncthreads();
      if ((w & 1) == half) {
        #pragma unroll
        for (int j = 0; j < 4; ++j) {
          const int colq = j * 16 + fr;          // 0..63 within half
          const float bv = bias[n0 + half * 64 + colq];
          #pragma unroll
          for (int i = 0; i < 4; ++i)
            #pragma unroll
            for (int rr = 0; rr < 4; ++rr)
              Ct[(wr + i * 16 + kg * 4 + rr) * 68 + colq] = acc[i][j][rr] + bv;
        }
      }
      __syncthreads();
      const int r = t >> 1, cb = (t & 1) * 32;
      const int gcol = n0 + half * 64 + cb;      // 32-aligned
      const int ht = gcol >> 8, dd = gcol & 255;
      _Float16* p = Cq + (size_t)(m0 + r) * (3 * HALFD * NHT) + ht * (3 * HALFD) + dd;
      #pragma unroll
      for (int u = 0; u < 32; u += 8) {
        float vv[8];
        *(float4*)&vv[0] = *(const float4*)&Ct[r * 68 + cb + u];
        *(float4*)&vv[4] = *(const float4*)&Ct[r * 68 + cb + u + 4];
        v8h hv, dv, mv;
        #pragma unroll
        for (int e = 0; e < 8; ++e) {
          const _Float16 hh = (_Float16)vv[e];
          hv[e] = hh;
          mv[e] = (_Float16)((vv[e] - (float)hh) * 64.0f);
          dv[e] = (_Float16)((float)hh * 0.015625f);
        }
        *(v8h*)(p + u) = hv;                    // h
        *(v8h*)(p + HALFD + u) = dv;            // h/64
        *(v8h*)(p + 2 * HALFD + u) = mv;        // m
      }
    }
  } else {
    float* Cb = Cf + (size_t)z * cBS;
    #pragma unroll
    for (int i = 0; i < 4; ++i)
      #pragma unroll
      for (int j = 0; j < 4; ++j)
        #pragma unroll
        for (int rr = 0; rr < 4; ++rr) {
          const int rowg = m0 + wr + i * 16 + kg * 4 + rr;
          const int colg = n0 + wc + j * 16 + fr;
          Cb[(size_t)rowg * ldc + colg] = acc[i][j][rr];
        }
  }
}

// ====== topk1 (x2 rows) + topk2 + softmax + gather, one block per token ======
// Wave h handles ht rows 2h, 2h+1 (exactly the rows head h needs). Identical
// scan order / tie rules as the separate kernels => bit-identical selection.
__global__ __launch_bounds__(256) void topk_all_gather_kernel(
    const float* __restrict__ S, const float* __restrict__ values,
    float* __restrict__ out) {
  __shared__ float ls1[4][32], ls2[4][32], sels[4][32];
  __shared__ int   li1[4][32], li2[4][32], seli[4][32];
  __shared__ float lw[128];
  __shared__ int   lidx[128];
  const int b = blockIdx.x, t = threadIdx.x;
  const int lane = t & 63, h = t >> 6;
  const float* srA = S + ((size_t)b * NHT + 2 * h) * NKEYS;
  const float* srB = srA + NKEYS;
  float va[8], vb[8];
  #pragma unroll
  for (int j = 0; j < 8; ++j) va[j] = srA[j * 64 + lane];
  #pragma unroll
  for (int j = 0; j < 8; ++j) vb[j] = srB[j * 64 + lane];

  // ---- top-32 of row A (ht=2h) ----
  for (int r = 0; r < KNN; ++r) {
    float bv = -INFINITY; int bi = 0x7fffffff;
    #pragma unroll
    for (int j = 0; j < 8; ++j) {
      const int idx = j * 64 + lane;
      if (va[j] > bv) { bv = va[j]; bi = idx; }
    }
    #pragma unroll
    for (int off = 32; off > 0; off >>= 1) {
      const float ov = __shfl_xor(bv, off);
      const int oi = __shfl_xor(bi, off);
      if (ov > bv || (ov == bv && oi < bi)) { bv = ov; bi = oi; }
    }
    if (lane == 0) { ls1[h][r] = bv; li1[h][r] = bi; }
    const int jj = bi >> 6;
    const bool mine = (bi & 63) == lane;
    #pragma unroll
    for (int j = 0; j < 8; ++j)
      if (mine && j == jj) va[j] = -INFINITY;
  }
  // ---- top-32 of row B (ht=2h+1) ----
  for (int r = 0; r < KNN; ++r) {
    float bv = -INFINITY; int bi = 0x7fffffff;
    #pragma unroll
    for (int j = 0; j < 8; ++j) {
      const int idx = j * 64 + lane;
      if (vb[j] > bv) { bv = vb[j]; bi = idx; }
    }
    #pragma unroll
    for (int off = 32; off > 0; off >>= 1) {
      const float ov = __shfl_xor(bv, off);
      const int oi = __shfl_xor(bi, off);
      if (ov > bv || (ov == bv && oi < bi)) { bv = ov; bi = oi; }
    }
    if (lane == 0) { ls2[h][r] = bv; li2[h][r] = bi; }
    const int jj = bi >> 6;
    const bool mine = (bi & 63) == lane;
    #pragma unroll
    for (int j = 0; j < 8; ++j)
      if (mine && j == jj) vb[j] = -INFINITY;
  }

  // ---- cartesian top-32 of 1024 (head h) ----
  float v[16];
  #pragma unroll
  for (int c = 0; c < 16; ++c) {
    const int p = c * 64 + lane;
    v[c] = ls1[h][p >> 5] + ls2[h][p & 31];
  }
  for (int r = 0; r < KNN; ++r) {
    float bv = -INFINITY; int bp = 0x7fffffff;
    #pragma unroll
    for (int c = 0; c < 16; ++c) {
      const int p = c * 64 + lane;
      if (v[c] > bv) { bv = v[c]; bp = p; }
    }
    #pragma unroll
    for (int off = 32; off > 0; off >>= 1) {
      const float ov = __shfl_xor(bv, off);
      const int op = __shfl_xor(bp, off);
      if (ov > bv || (ov == bv && op < bp)) { bv = ov; bp = op; }
    }
    if (lane == 0) {
      sels[h][r] = bv;
      seli[h][r] = li1[h][bp >> 5] * NKEYS + li2[h][bp & 31];
    }
    const int cc = bp >> 6;
    const bool mine = (bp & 63) == lane;
    #pragma unroll
    for (int c = 0; c < 16; ++c)
      if (mine && c == cc) v[c] = -INFINITY;
  }
  const float m = sels[h][0];
  const float e = (lane < 32) ? expf(sels[h][lane] - m) : 0.0f;
  float s = e;
  #pragma unroll
  for (int off = 32; off > 0; off >>= 1) s += __shfl_xor(s, off);
  if (lane < 32) {
    lw[h * 32 + lane] = e / s;
    lidx[h * 32 + lane] = seli[h][lane];
  }
  __syncthreads();
  // ---- gather ----
  const int d0 = t * 4;
  float4 acc = {0.f, 0.f, 0.f, 0.f};
  #pragma unroll 8
  for (int k = 0; k < 128; ++k) {
    const float4 vv = *(const float4*)&values[(size_t)lidx[k] * VDIM + d0];
    const float ww = lw[k];
    acc.x = fmaf(ww, vv.x, acc.x);
    acc.y = fmaf(ww, vv.y, acc.y);
    acc.z = fmaf(ww, vv.z, acc.z);
    acc.w = fmaf(ww, vv.w, acc.w);
  }
  *(float4*)&out[(size_t)b * VDIM + d0] = acc;
}

extern "C" void kernel_launch(void* const* d_in, const int* in_sizes, int n_in,
                              void* d_out, int out_size, void* d_ws, size_t ws_size,
                              hipStream_t stream) {
  const float* x      = (const float*)d_in[0];
  const float* w_q    = (const float*)d_in[1];
  const float* b_q    = (const float*)d_in[2];
  const float* keys   = (const float*)d_in[3];
  const float* values = (const float*)d_in[4];
  float* out = (float*)d_out;

  char* ws = (char*)d_ws;
  _Float16* xs    = (_Float16*)(ws);                  // 2048*3072*2 = 12.6 MB
  _Float16* wqs   = (_Float16*)(ws + (16u  << 20));   // 12.6 MB
  _Float16* keyss = (_Float16*)(ws + (32u  << 20));   // 4096*768*2 = 6.3 MB
  _Float16* Qs    = (_Float16*)(ws + (40u  << 20));   // 2048*6144*2 = 25.2 MB
  float*    S     = (float*)   (ws + (68u  << 20));   // 2048*4096*4 = 32 MB

  split_all_kernel<<<5120, 256, 0, stream>>>(x, w_q, keys, xs, wqs, keyss);

  // GEMM1: Q'' = split(x'' @ w_q''^T + b) : M=2048, N=2048, K'=3072
  mfma_gemm<true><<<dim3(QDIM / 128, BSZ / 128, 1), 256, 0, stream>>>(
      xs, 3 * INDIM, 0, wqs, 3 * INDIM, 0, b_q,
      nullptr, 0, 0, Qs, 3 * INDIM);
  // GEMM2: S = Q'' @ keys''^T : 8 x (M=2048, N=512, K'=768)
  mfma_gemm<false><<<dim3(NKEYS / 128, BSZ / 128, NHT), 256, 0, stream>>>(
      Qs, 3 * HALFD * NHT, 3 * HALFD, keyss, 3 * HALFD, (long)NKEYS * 3 * HALFD, nullptr,
      S, NHT * NKEYS, NKEYS, nullptr, 3 * HALFD);

  topk_all_gather_kernel<<<BSZ, 256, 0, stream>>>(S, values, out);
}